// Round 13
// baseline (361.385 us; speedup 1.0000x reference)
//
#include <hip/hip_runtime.h>
#include <hip/hip_bf16.h>
#include <math.h>

#define KD 1024
#define VD 50000
#define BD 2048
#define WDIM 20
#define THRV 1e-10f
#define PI_F 3.14159274101257324f  /* 0x40490FDB — f32(pi) */

#define CH 8192            /* complex elements per chunk (64 KB) */
#define NCH 7              /* 6 full chunks + tail */
#define TAILC 848          /* 50000 - 6*8192 */

// d_out is FLOAT32[2049]: [0..2048) = mu (as float), [2048] = E.
//
// LESSONS: (r8-r10) inline-asm/global_load_lds -> per-thread arrays go to
// scratch (WRITE 419-656MB). Plain HIP keeps them in AGPRs (r6/r11: 8.2MB).
// (r11) XCD sibling swizzle works: FETCH 430->207MB. Quarter-split's 4x
// stream redundancy cost more than its TLP gained -> use 2-half split with
// single-barrier double-buffered LDS instead.
// (r12) infra failure (UnresponsiveContainer) — this is the r12 kernel
// resubmitted unchanged.

// ---------------------------------------------------------------------------
// Kernel P: b-minor tables. cst[w][b] = (cos,sin)(pi*pos[b][w]);
// idp[j][b] = ids[b][2j] | ids[b][2j+1]<<16. Same trig ops as passing rounds.
// ---------------------------------------------------------------------------
__global__ __launch_bounds__(256) void prep_kernel(
    const float* __restrict__ pos,
    const int*   __restrict__ ids,
    float2* __restrict__ cst,
    unsigned int* __restrict__ idp)
{
    const int b = blockIdx.x * 256 + threadIdx.x;
    if (b >= BD) return;
    int idv[WDIM];
#pragma unroll
    for (int w = 0; w < WDIM; ++w) {
        idv[w] = ids[b * WDIM + w];
        const float pf = __fmul_rn(pos[b * WDIM + w], PI_F);
        cst[w * BD + b] = make_float2(cosf(pf), sinf(pf));
    }
#pragma unroll
    for (int j = 0; j < WDIM / 2; ++j)
        idp[j * BD + b] = (unsigned int)idv[2 * j] |
                          ((unsigned int)idv[2 * j + 1] << 16);
}

// ---------------------------------------------------------------------------
// Kernel B: grid 2048 = (row k) x (half of B). 1024 threads, 1 b/thread.
// Double-buffered 2x64KB LDS, ONE barrier per chunk: at loop top buf[p] is
// ready and buf[p^1] is free (its readers finished an iteration ago).
// Per chunk: pf-load c+1 (latency hides under match), match c, store pf.
// XCD swizzle: both halves of row k adjacent on one XCD -> L2 share.
// Score math bit-identical to rounds 5-11 (pairwise-8, _rn ops).
// ---------------------------------------------------------------------------
__global__ __launch_bounds__(1024) void half_kernel(
    const float* __restrict__ W,
    const unsigned int* __restrict__ idp,
    const float2* __restrict__ cst,
    float* __restrict__ norm2,
    float* __restrict__ scores)   // [KD][BD]
{
    __shared__ __align__(16) float4 buf[2][(CH * 2) / 4];   // 2 x 64 KB
    __shared__ float sm[16];

    const int t = threadIdx.x;
    // swizzle: xcd = g&7; slot = g>>3; k = xcd + 8*(slot>>1); half = slot&1
    const int g    = blockIdx.x;
    const int slot = g >> 3;
    const int k    = (g & 7) + 8 * (slot >> 1);
    const int half = slot & 1;
    const int b    = half * 1024 + t;

    const float* Wk = W + (size_t)k * (VD * 2);

    unsigned int idreg[WDIM / 2];
#pragma unroll
    for (int j = 0; j < WDIM / 2; ++j) idreg[j] = idp[j * BD + b];

    float gx[WDIM], gy[WDIM];
#pragma unroll
    for (int w = 0; w < WDIM; ++w) { gx[w] = 0.f; gy[w] = 0.f; }

    float nacc = 0.0f;

    // prologue: stream chunk 0 -> buf[0] (load->store, norm accumulated)
    {
        const float4* src = reinterpret_cast<const float4*>(Wk);
#pragma unroll
        for (int j = 0; j < 4; ++j) {
            const float4 v = src[t + j * 1024];
            buf[0][t + j * 1024] = v;
            nacc += v.x * v.x + v.y * v.y + v.z * v.z + v.w * v.w;
        }
    }

    for (int c = 0; c < NCH; ++c) {
        const int p = c & 1;
        const bool istail = (c == NCH - 1);

        __syncthreads();   // buf[p] ready; buf[p^1] free (readers done c-1)

        // ---- load next chunk into regs (flies under the match below) ----
        float4 pf0, pf1, pf2, pf3;
        bool have[4] = {false, false, false, false};
        if (!istail) {
            const int nf4n = (c + 1 == NCH - 1) ? (TAILC * 2) / 4 : (CH * 2) / 4;
            const float4* src = reinterpret_cast<const float4*>(
                Wk + (size_t)(c + 1) * (CH * 2));
            if (t + 0 * 1024 < nf4n) { pf0 = src[t + 0 * 1024]; have[0] = true; }
            if (t + 1 * 1024 < nf4n) { pf1 = src[t + 1 * 1024]; have[1] = true; }
            if (t + 2 * 1024 < nf4n) { pf2 = src[t + 2 * 1024]; have[2] = true; }
            if (t + 3 * 1024 < nf4n) { pf3 = src[t + 3 * 1024]; have[3] = true; }
        }

        // ---- predicated match of chunk c from buf[p] ----
        const float* ch = reinterpret_cast<const float*>(buf[p]);
        const int lo = c * CH;
        const unsigned lim = istail ? TAILC : CH;
#pragma unroll
        for (int w = 0; w < WDIM; ++w) {
            const int id = (int)((idreg[w >> 1] >> ((w & 1) * 16)) & 0xFFFFu);
            const unsigned off = (unsigned)(id - lo);
            if (off < lim) {
                gx[w] = ch[2 * off];
                gy[w] = ch[2 * off + 1];
            }
        }

        // ---- store prefetched chunk c+1 into buf[p^1] + norm accum ----
        if (!istail) {
            if (have[0]) { buf[p ^ 1][t + 0 * 1024] = pf0;
                nacc += pf0.x * pf0.x + pf0.y * pf0.y + pf0.z * pf0.z + pf0.w * pf0.w; }
            if (have[1]) { buf[p ^ 1][t + 1 * 1024] = pf1;
                nacc += pf1.x * pf1.x + pf1.y * pf1.y + pf1.z * pf1.z + pf1.w * pf1.w; }
            if (have[2]) { buf[p ^ 1][t + 2 * 1024] = pf2;
                nacc += pf2.x * pf2.x + pf2.y * pf2.y + pf2.z * pf2.z + pf2.w * pf2.w; }
            if (have[3]) { buf[p ^ 1][t + 3 * 1024] = pf3;
                nacc += pf3.x * pf3.x + pf3.y * pf3.y + pf3.z * pf3.z + pf3.w * pf3.w; }
        }
    }

    // ---- norm2 reduce (full row per block; write once from half 0) ----
#pragma unroll
    for (int off = 32; off > 0; off >>= 1) nacc += __shfl_down(nacc, off, 64);
    if ((t & 63) == 0) sm[t >> 6] = nacc;
    __syncthreads();
    if (t == 0 && half == 0) {
        float s = 0.0f;
#pragma unroll
        for (int i = 0; i < 16; ++i) s += sm[i];
        norm2[k] = s;
    }

    // ---- score math (exact numpy pairwise-8 order) ----
    {
        float phi[WDIM];
#pragma unroll
        for (int w = 0; w < WDIM; ++w) {
            const float2 cs = cst[w * BD + b];
            const float x = gx[w], y = gy[w];
            const float mag = hypotf(x, y);
            const float re  = __fadd_rn(__fmul_rn(x, cs.x), __fmul_rn(y, cs.y));
            const float im  = __fsub_rn(__fmul_rn(y, cs.x), __fmul_rn(x, cs.y));
            phi[w] = __fadd_rn(mag, fabsf(atan2f(im, re)));
        }
        const float r0 = __fadd_rn(phi[0], phi[8]);
        const float r1 = __fadd_rn(phi[1], phi[9]);
        const float r2 = __fadd_rn(phi[2], phi[10]);
        const float r3 = __fadd_rn(phi[3], phi[11]);
        const float r4 = __fadd_rn(phi[4], phi[12]);
        const float r5 = __fadd_rn(phi[5], phi[13]);
        const float r6 = __fadd_rn(phi[6], phi[14]);
        const float r7 = __fadd_rn(phi[7], phi[15]);
        float score = __fadd_rn(__fadd_rn(__fadd_rn(r0, r1), __fadd_rn(r2, r3)),
                                __fadd_rn(__fadd_rn(r4, r5), __fadd_rn(r6, r7)));
        score = __fadd_rn(score, phi[16]);
        score = __fadd_rn(score, phi[17]);
        score = __fadd_rn(score, phi[18]);
        score = __fadd_rn(score, phi[19]);
        scores[(size_t)k * BD + b] = score;
    }
}

// ---------------------------------------------------------------------------
// Kernel C: argmax over k per batch (coalesced). Strict >, tie -> smallest k.
// ---------------------------------------------------------------------------
__global__ __launch_bounds__(256) void argmax_kernel(
    const float* __restrict__ scores,
    float* __restrict__ out,
    int*   __restrict__ mu_int)
{
    const int b = blockIdx.x * 256 + threadIdx.x;
    float best = -3.402823466e+38f;
    int   bi   = 0;
    for (int k = 0; k < KD; ++k) {
        const float v = scores[(size_t)k * BD + b];
        if (v > best) { best = v; bi = k; }
    }
    mu_int[b] = bi;
    out[b] = (float)bi;
}

// ---------------------------------------------------------------------------
// Kernel D: per-batch energy contribution
// ---------------------------------------------------------------------------
__global__ __launch_bounds__(64) void e_kernel(
    const float* __restrict__ W,
    const float* __restrict__ Ps,
    const float* __restrict__ pos,
    const int*   __restrict__ ids,
    const int*   __restrict__ mu_int,
    const float* __restrict__ norm2,
    float* __restrict__ contrib)
{
    const int b = blockIdx.x;
    const int t = threadIdx.x;
    const int mu = mu_int[b];
    const float* Wm = W + (size_t)mu * (VD * 2);

    float loc_abs = 0.0f, loc_phi = 0.0f;
    if (t < WDIM) {
        const int id = ids[b * WDIM + t];
        const float P = Ps[b * WDIM + t];
        const float pf = __fmul_rn(pos[b * WDIM + t], PI_F);
        const float c = cosf(pf), s = sinf(pf);
        const float2 g = *reinterpret_cast<const float2*>(Wm + 2 * (size_t)id);
        float re = P * (g.x * c + g.y * s);
        float im = P * (g.y * c - g.x * s);
        if (re < THRV && re > -THRV) re = THRV;
        if (im < THRV && im > -THRV) im = THRV;
        loc_abs = sqrtf(re * re + im * im);
        loc_phi = fabsf(atan2f(im, re)) * P;
    }
#pragma unroll
    for (int off = 32; off > 0; off >>= 1) {
        loc_abs += __shfl_down(loc_abs, off, 64);
        loc_phi += __shfl_down(loc_phi, off, 64);
    }
    if (t == 0) {
        const float den = sqrtf(norm2[mu]);
        contrib[b] = loc_abs / den + loc_phi;
    }
}

// ---------------------------------------------------------------------------
// Kernel E: deterministic final reduction (f64 accum), E -> out[2048]
// ---------------------------------------------------------------------------
__global__ __launch_bounds__(256) void finalize_kernel(
    const float* __restrict__ contrib,
    float* __restrict__ out)
{
    __shared__ double sm[4];
    double acc = 0.0;
    for (int i = threadIdx.x; i < BD; i += 256) acc += (double)contrib[i];
#pragma unroll
    for (int off = 32; off > 0; off >>= 1) acc += __shfl_down(acc, off, 64);
    if ((threadIdx.x & 63) == 0) sm[threadIdx.x >> 6] = acc;
    __syncthreads();
    if (threadIdx.x == 0) {
        double s = sm[0] + sm[1] + sm[2] + sm[3];
        out[BD] = (float)(-s);
    }
}

// ---------------------------------------------------------------------------
// Fallback (round-5 passing path) if ws_size is too small
// ---------------------------------------------------------------------------
__global__ __launch_bounds__(1024) void scores_kernel_fb(
    const float* __restrict__ W,
    const float* __restrict__ pos,
    const int*   __restrict__ ids,
    float* __restrict__ out,
    int* __restrict__ mu_int)
{
    __shared__ int   s_id[WDIM];
    __shared__ float s_c[WDIM];
    __shared__ float s_s[WDIM];
    __shared__ float r_val[16];
    __shared__ int   r_idx[16];

    const int b = blockIdx.x;
    const int t = threadIdx.x;

    if (t < WDIM) {
        s_id[t] = ids[b * WDIM + t];
        const float pf = __fmul_rn(pos[b * WDIM + t], PI_F);
        s_c[t] = cosf(pf);
        s_s[t] = sinf(pf);
    }
    __syncthreads();

    const float* Wk = W + (size_t)t * (VD * 2);
    float phi[WDIM];
#pragma unroll
    for (int w = 0; w < WDIM; ++w) {
        const float2 g = *reinterpret_cast<const float2*>(Wk + 2 * (size_t)s_id[w]);
        const float c = s_c[w], s = s_s[w];
        const float mag = hypotf(g.x, g.y);
        const float re = __fadd_rn(__fmul_rn(g.x, c), __fmul_rn(g.y, s));
        const float im = __fsub_rn(__fmul_rn(g.y, c), __fmul_rn(g.x, s));
        phi[w] = __fadd_rn(mag, fabsf(atan2f(im, re)));
    }
    const float r0 = __fadd_rn(phi[0], phi[8]);
    const float r1 = __fadd_rn(phi[1], phi[9]);
    const float r2 = __fadd_rn(phi[2], phi[10]);
    const float r3 = __fadd_rn(phi[3], phi[11]);
    const float r4 = __fadd_rn(phi[4], phi[12]);
    const float r5 = __fadd_rn(phi[5], phi[13]);
    const float r6 = __fadd_rn(phi[6], phi[14]);
    const float r7 = __fadd_rn(phi[7], phi[15]);
    float score = __fadd_rn(__fadd_rn(__fadd_rn(r0, r1), __fadd_rn(r2, r3)),
                            __fadd_rn(__fadd_rn(r4, r5), __fadd_rn(r6, r7)));
    score = __fadd_rn(score, phi[16]);
    score = __fadd_rn(score, phi[17]);
    score = __fadd_rn(score, phi[18]);
    score = __fadd_rn(score, phi[19]);

    float v = score; int vi = t;
#pragma unroll
    for (int off = 32; off > 0; off >>= 1) {
        float ov = __shfl_down(v, off, 64);
        int   oi = __shfl_down(vi, off, 64);
        if (ov > v || (ov == v && oi < vi)) { v = ov; vi = oi; }
    }
    if ((t & 63) == 0) { r_val[t >> 6] = v; r_idx[t >> 6] = vi; }
    __syncthreads();
    if (t == 0) {
        float bv = r_val[0]; int bi = r_idx[0];
#pragma unroll
        for (int i = 1; i < 16; ++i) {
            if (r_val[i] > bv || (r_val[i] == bv && r_idx[i] < bi)) {
                bv = r_val[i]; bi = r_idx[i];
            }
        }
        mu_int[b] = bi;
        out[b] = (float)bi;
    }
}

__global__ __launch_bounds__(512) void norm_kernel_fb(
    const float* __restrict__ W,
    float* __restrict__ norm2)
{
    const int k = blockIdx.x;
    const float4* row = reinterpret_cast<const float4*>(W + (size_t)k * (VD * 2));
    const int n4 = (VD * 2) / 4;
    float acc = 0.0f;
    for (int i = threadIdx.x; i < n4; i += 512) {
        float4 v = row[i];
        acc += v.x * v.x + v.y * v.y + v.z * v.z + v.w * v.w;
    }
    __shared__ float sm[8];
#pragma unroll
    for (int off = 32; off > 0; off >>= 1) acc += __shfl_down(acc, off, 64);
    if ((threadIdx.x & 63) == 0) sm[threadIdx.x >> 6] = acc;
    __syncthreads();
    if (threadIdx.x == 0) {
        float s = 0.0f;
#pragma unroll
        for (int i = 0; i < 8; ++i) s += sm[i];
        norm2[k] = s;
    }
}

extern "C" void kernel_launch(void* const* d_in, const int* in_sizes, int n_in,
                              void* d_out, int out_size, void* d_ws, size_t ws_size,
                              hipStream_t stream) {
    const float* W   = (const float*)d_in[0];  // (K, V, 2) fp32
    const float* Ps  = (const float*)d_in[1];  // (B, WD) fp32
    const float* pos = (const float*)d_in[2];  // (B, WD) fp32
    const int*   ids = (const int*)d_in[3];    // (B, WD) int32

    float* out = (float*)d_out;                // float32[2049]

    // ws layout
    float2*       cst     = (float2*)d_ws;                         // WD*BD float2
    unsigned int* idp     = (unsigned int*)(cst + WDIM * BD);      // (WD/2)*BD u32
    float*        norm2   = (float*)(idp + (WDIM / 2) * BD);       // KD
    float*        contrib = norm2 + KD;                            // BD
    int*          mu_int  = (int*)(contrib + BD);                  // BD
    float*        scores  = (float*)(mu_int + BD);                 // KD*BD
    const size_t need = (size_t)(WDIM * BD * 2 + (WDIM / 2) * BD + KD + 2 * BD) * 4
                      + (size_t)KD * BD * 4;

    if (ws_size >= need) {
        prep_kernel<<<(BD + 255) / 256, 256, 0, stream>>>(pos, ids, cst, idp);
        half_kernel<<<KD * 2, 1024, 0, stream>>>(W, idp, cst, norm2, scores);
        argmax_kernel<<<BD / 256, 256, 0, stream>>>(scores, out, mu_int);
    } else {
        scores_kernel_fb<<<BD, 1024, 0, stream>>>(W, pos, ids, out, mu_int);
        norm_kernel_fb<<<KD, 512, 0, stream>>>(W, norm2);
    }
    e_kernel<<<BD, 64, 0, stream>>>(W, Ps, pos, ids, mu_int, norm2, contrib);
    finalize_kernel<<<1, 256, 0, stream>>>(contrib, out);
}

// Round 14
// 249.646 us; speedup vs baseline: 1.4476x; 1.4476x over previous
//
#include <hip/hip_runtime.h>
#include <hip/hip_bf16.h>
#include <math.h>

#define KD 1024
#define VD 50000
#define BD 2048
#define WDIM 20
#define THRV 1e-10f
#define PI_F 3.14159274101257324f  /* 0x40490FDB — f32(pi) */

#define CH 8192            /* complex elements per chunk (64 KB) */
#define NCH 7              /* 6 full chunks + tail */
#define TAILC 848          /* 50000 - 6*8192 */

// d_out is FLOAT32[2049]: [0..2048) = mu (as float), [2048] = E.
//
// SPILL MATRIX (key lesson): 1024-thr blocks cap at 128 VGPR/thread ->
// r13's dbuf+pf state spilled (WRITE 545MB). 512-thr blocks at 1 block/CU
// (launch_bounds(512,2) -> 2 waves/SIMD) get a 256-reg budget -> r11 ran
// clean (VGPR 56, WRITE 8.2MB). So: dbuf+prefetch pipeline at 512 threads.
// Match phase stays copy-only (predicated atan2 in-chunk = 7x VALU waste).

// ---------------------------------------------------------------------------
// Kernel P: b-minor tables. cst[w][b] = (cos,sin)(pi*pos[b][w]);
// idp[j][b] = ids[b][2j] | ids[b][2j+1]<<16. Same trig ops as passing rounds.
// ---------------------------------------------------------------------------
__global__ __launch_bounds__(256) void prep_kernel(
    const float* __restrict__ pos,
    const int*   __restrict__ ids,
    float2* __restrict__ cst,
    unsigned int* __restrict__ idp)
{
    const int b = blockIdx.x * 256 + threadIdx.x;
    if (b >= BD) return;
    int idv[WDIM];
#pragma unroll
    for (int w = 0; w < WDIM; ++w) {
        idv[w] = ids[b * WDIM + w];
        const float pf = __fmul_rn(pos[b * WDIM + w], PI_F);
        cst[w * BD + b] = make_float2(cosf(pf), sinf(pf));
    }
#pragma unroll
    for (int j = 0; j < WDIM / 2; ++j)
        idp[j * BD + b] = (unsigned int)idv[2 * j] |
                          ((unsigned int)idv[2 * j + 1] << 16);
}

// ---------------------------------------------------------------------------
// Kernel B: grid 2048 = (row k) x (half of B). 512 threads, 2 b/thread.
// launch_bounds(512,2): 1 block/CU, 256-VGPR budget -> 80-float g-state +
// pf[8] prefetch regs stay in registers. Double-buffered 2x64KB LDS, ONE
// barrier per chunk; pf-load of chunk c+1 issued before match of chunk c.
// XCD swizzle: both halves of row k adjacent on one XCD -> L2 share.
// Score math bit-identical to rounds 5-13 (pairwise-8, _rn ops).
// ---------------------------------------------------------------------------
__global__ __launch_bounds__(512, 2) void half_kernel(
    const float* __restrict__ W,
    const unsigned int* __restrict__ idp,
    const float2* __restrict__ cst,
    float* __restrict__ norm2,
    float* __restrict__ scores)   // [KD][BD]
{
    __shared__ __align__(16) float4 buf[2][(CH * 2) / 4];   // 2 x 64 KB
    __shared__ float sm[8];

    const int t = threadIdx.x;
    // swizzle: xcd = g&7; slot = g>>3; k = xcd + 8*(slot>>1); half = slot&1
    const int g    = blockIdx.x;
    const int slot = g >> 3;
    const int k    = (g & 7) + 8 * (slot >> 1);
    const int half = slot & 1;
    const int b0   = half * 1024 + t;        // this thread's two batches:
    const int b1   = b0 + 512;               // b0 and b0+512

    const float* Wk = W + (size_t)k * (VD * 2);

    unsigned int idreg[2][WDIM / 2];
#pragma unroll
    for (int j = 0; j < WDIM / 2; ++j) {
        idreg[0][j] = idp[j * BD + b0];
        idreg[1][j] = idp[j * BD + b1];
    }

    float gx[2][WDIM], gy[2][WDIM];
#pragma unroll
    for (int w = 0; w < WDIM; ++w) {
        gx[0][w] = 0.f; gy[0][w] = 0.f; gx[1][w] = 0.f; gy[1][w] = 0.f;
    }

    float nacc = 0.0f;

    // prologue: stream chunk 0 -> buf[0] (8 float4 per thread)
    {
        const float4* src = reinterpret_cast<const float4*>(Wk);
#pragma unroll
        for (int j = 0; j < 8; ++j) {
            const float4 v = src[t + j * 512];
            buf[0][t + j * 512] = v;
            nacc += v.x * v.x + v.y * v.y + v.z * v.z + v.w * v.w;
        }
    }

    for (int c = 0; c < NCH; ++c) {
        const int p = c & 1;
        const bool istail = (c == NCH - 1);

        __syncthreads();   // buf[p] ready; buf[p^1] free (readers done at c-1)

        // ---- issue next chunk's loads into regs (fly under the match) ----
        float4 pf[8];
        int nf4n = 0;
        if (!istail) {
            nf4n = (c + 1 == NCH - 1) ? (TAILC * 2) / 4 : (CH * 2) / 4;
            const float4* src = reinterpret_cast<const float4*>(
                Wk + (size_t)(c + 1) * (CH * 2));
#pragma unroll
            for (int j = 0; j < 8; ++j) {
                const int i = t + j * 512;
                if (i < nf4n) pf[j] = src[i];
            }
        }

        // ---- predicated copy-only match of chunk c from buf[p] ----
        const float* ch = reinterpret_cast<const float*>(buf[p]);
        const int lo = c * CH;
        const unsigned lim = istail ? TAILC : CH;
#pragma unroll
        for (int bb = 0; bb < 2; ++bb) {
#pragma unroll
            for (int w = 0; w < WDIM; ++w) {
                const int id = (int)((idreg[bb][w >> 1] >> ((w & 1) * 16)) & 0xFFFFu);
                const unsigned off = (unsigned)(id - lo);
                if (off < lim) {
                    gx[bb][w] = ch[2 * off];
                    gy[bb][w] = ch[2 * off + 1];
                }
            }
        }

        // ---- store prefetched chunk c+1 into buf[p^1] + norm accum ----
        if (!istail) {
#pragma unroll
            for (int j = 0; j < 8; ++j) {
                const int i = t + j * 512;
                if (i < nf4n) {
                    const float4 v = pf[j];
                    buf[p ^ 1][i] = v;
                    nacc += v.x * v.x + v.y * v.y + v.z * v.z + v.w * v.w;
                }
            }
        }
    }

    // ---- norm2 reduce (full row per block; write once from half 0) ----
#pragma unroll
    for (int off = 32; off > 0; off >>= 1) nacc += __shfl_down(nacc, off, 64);
    if ((t & 63) == 0) sm[t >> 6] = nacc;
    __syncthreads();
    if (t == 0 && half == 0) {
        float s = 0.0f;
#pragma unroll
        for (int i = 0; i < 8; ++i) s += sm[i];
        norm2[k] = s;
    }

    // ---- score math (divergence-free, exact numpy pairwise-8 order) ----
#pragma unroll
    for (int bb = 0; bb < 2; ++bb) {
        const int b = (bb == 0) ? b0 : b1;
        float phi[WDIM];
#pragma unroll
        for (int w = 0; w < WDIM; ++w) {
            const float2 cs = cst[w * BD + b];
            const float x = gx[bb][w], y = gy[bb][w];
            const float mag = hypotf(x, y);
            const float re  = __fadd_rn(__fmul_rn(x, cs.x), __fmul_rn(y, cs.y));
            const float im  = __fsub_rn(__fmul_rn(y, cs.x), __fmul_rn(x, cs.y));
            phi[w] = __fadd_rn(mag, fabsf(atan2f(im, re)));
        }
        const float r0 = __fadd_rn(phi[0], phi[8]);
        const float r1 = __fadd_rn(phi[1], phi[9]);
        const float r2 = __fadd_rn(phi[2], phi[10]);
        const float r3 = __fadd_rn(phi[3], phi[11]);
        const float r4 = __fadd_rn(phi[4], phi[12]);
        const float r5 = __fadd_rn(phi[5], phi[13]);
        const float r6 = __fadd_rn(phi[6], phi[14]);
        const float r7 = __fadd_rn(phi[7], phi[15]);
        float score = __fadd_rn(__fadd_rn(__fadd_rn(r0, r1), __fadd_rn(r2, r3)),
                                __fadd_rn(__fadd_rn(r4, r5), __fadd_rn(r6, r7)));
        score = __fadd_rn(score, phi[16]);
        score = __fadd_rn(score, phi[17]);
        score = __fadd_rn(score, phi[18]);
        score = __fadd_rn(score, phi[19]);
        scores[(size_t)k * BD + b] = score;
    }
}

// ---------------------------------------------------------------------------
// Kernel C: argmax over k per batch (coalesced). Strict >, tie -> smallest k.
// ---------------------------------------------------------------------------
__global__ __launch_bounds__(256) void argmax_kernel(
    const float* __restrict__ scores,
    float* __restrict__ out,
    int*   __restrict__ mu_int)
{
    const int b = blockIdx.x * 256 + threadIdx.x;
    float best = -3.402823466e+38f;
    int   bi   = 0;
    for (int k = 0; k < KD; ++k) {
        const float v = scores[(size_t)k * BD + b];
        if (v > best) { best = v; bi = k; }
    }
    mu_int[b] = bi;
    out[b] = (float)bi;
}

// ---------------------------------------------------------------------------
// Kernel D: per-batch energy contribution
// ---------------------------------------------------------------------------
__global__ __launch_bounds__(64) void e_kernel(
    const float* __restrict__ W,
    const float* __restrict__ Ps,
    const float* __restrict__ pos,
    const int*   __restrict__ ids,
    const int*   __restrict__ mu_int,
    const float* __restrict__ norm2,
    float* __restrict__ contrib)
{
    const int b = blockIdx.x;
    const int t = threadIdx.x;
    const int mu = mu_int[b];
    const float* Wm = W + (size_t)mu * (VD * 2);

    float loc_abs = 0.0f, loc_phi = 0.0f;
    if (t < WDIM) {
        const int id = ids[b * WDIM + t];
        const float P = Ps[b * WDIM + t];
        const float pf = __fmul_rn(pos[b * WDIM + t], PI_F);
        const float c = cosf(pf), s = sinf(pf);
        const float2 g = *reinterpret_cast<const float2*>(Wm + 2 * (size_t)id);
        float re = P * (g.x * c + g.y * s);
        float im = P * (g.y * c - g.x * s);
        if (re < THRV && re > -THRV) re = THRV;
        if (im < THRV && im > -THRV) im = THRV;
        loc_abs = sqrtf(re * re + im * im);
        loc_phi = fabsf(atan2f(im, re)) * P;
    }
#pragma unroll
    for (int off = 32; off > 0; off >>= 1) {
        loc_abs += __shfl_down(loc_abs, off, 64);
        loc_phi += __shfl_down(loc_phi, off, 64);
    }
    if (t == 0) {
        const float den = sqrtf(norm2[mu]);
        contrib[b] = loc_abs / den + loc_phi;
    }
}

// ---------------------------------------------------------------------------
// Kernel E: deterministic final reduction (f64 accum), E -> out[2048]
// ---------------------------------------------------------------------------
__global__ __launch_bounds__(256) void finalize_kernel(
    const float* __restrict__ contrib,
    float* __restrict__ out)
{
    __shared__ double sm[4];
    double acc = 0.0;
    for (int i = threadIdx.x; i < BD; i += 256) acc += (double)contrib[i];
#pragma unroll
    for (int off = 32; off > 0; off >>= 1) acc += __shfl_down(acc, off, 64);
    if ((threadIdx.x & 63) == 0) sm[threadIdx.x >> 6] = acc;
    __syncthreads();
    if (threadIdx.x == 0) {
        double s = sm[0] + sm[1] + sm[2] + sm[3];
        out[BD] = (float)(-s);
    }
}

// ---------------------------------------------------------------------------
// Fallback (round-5 passing path) if ws_size is too small
// ---------------------------------------------------------------------------
__global__ __launch_bounds__(1024) void scores_kernel_fb(
    const float* __restrict__ W,
    const float* __restrict__ pos,
    const int*   __restrict__ ids,
    float* __restrict__ out,
    int* __restrict__ mu_int)
{
    __shared__ int   s_id[WDIM];
    __shared__ float s_c[WDIM];
    __shared__ float s_s[WDIM];
    __shared__ float r_val[16];
    __shared__ int   r_idx[16];

    const int b = blockIdx.x;
    const int t = threadIdx.x;

    if (t < WDIM) {
        s_id[t] = ids[b * WDIM + t];
        const float pf = __fmul_rn(pos[b * WDIM + t], PI_F);
        s_c[t] = cosf(pf);
        s_s[t] = sinf(pf);
    }
    __syncthreads();

    const float* Wk = W + (size_t)t * (VD * 2);
    float phi[WDIM];
#pragma unroll
    for (int w = 0; w < WDIM; ++w) {
        const float2 g = *reinterpret_cast<const float2*>(Wk + 2 * (size_t)s_id[w]);
        const float c = s_c[w], s = s_s[w];
        const float mag = hypotf(g.x, g.y);
        const float re = __fadd_rn(__fmul_rn(g.x, c), __fmul_rn(g.y, s));
        const float im = __fsub_rn(__fmul_rn(g.y, c), __fmul_rn(g.x, s));
        phi[w] = __fadd_rn(mag, fabsf(atan2f(im, re)));
    }
    const float r0 = __fadd_rn(phi[0], phi[8]);
    const float r1 = __fadd_rn(phi[1], phi[9]);
    const float r2 = __fadd_rn(phi[2], phi[10]);
    const float r3 = __fadd_rn(phi[3], phi[11]);
    const float r4 = __fadd_rn(phi[4], phi[12]);
    const float r5 = __fadd_rn(phi[5], phi[13]);
    const float r6 = __fadd_rn(phi[6], phi[14]);
    const float r7 = __fadd_rn(phi[7], phi[15]);
    float score = __fadd_rn(__fadd_rn(__fadd_rn(r0, r1), __fadd_rn(r2, r3)),
                            __fadd_rn(__fadd_rn(r4, r5), __fadd_rn(r6, r7)));
    score = __fadd_rn(score, phi[16]);
    score = __fadd_rn(score, phi[17]);
    score = __fadd_rn(score, phi[18]);
    score = __fadd_rn(score, phi[19]);

    float v = score; int vi = t;
#pragma unroll
    for (int off = 32; off > 0; off >>= 1) {
        float ov = __shfl_down(v, off, 64);
        int   oi = __shfl_down(vi, off, 64);
        if (ov > v || (ov == v && oi < vi)) { v = ov; vi = oi; }
    }
    if ((t & 63) == 0) { r_val[t >> 6] = v; r_idx[t >> 6] = vi; }
    __syncthreads();
    if (t == 0) {
        float bv = r_val[0]; int bi = r_idx[0];
#pragma unroll
        for (int i = 1; i < 16; ++i) {
            if (r_val[i] > bv || (r_val[i] == bv && r_idx[i] < bi)) {
                bv = r_val[i]; bi = r_idx[i];
            }
        }
        mu_int[b] = bi;
        out[b] = (float)bi;
    }
}

__global__ __launch_bounds__(512) void norm_kernel_fb(
    const float* __restrict__ W,
    float* __restrict__ norm2)
{
    const int k = blockIdx.x;
    const float4* row = reinterpret_cast<const float4*>(W + (size_t)k * (VD * 2));
    const int n4 = (VD * 2) / 4;
    float acc = 0.0f;
    for (int i = threadIdx.x; i < n4; i += 512) {
        float4 v = row[i];
        acc += v.x * v.x + v.y * v.y + v.z * v.z + v.w * v.w;
    }
    __shared__ float sm[8];
#pragma unroll
    for (int off = 32; off > 0; off >>= 1) acc += __shfl_down(acc, off, 64);
    if ((threadIdx.x & 63) == 0) sm[threadIdx.x >> 6] = acc;
    __syncthreads();
    if (threadIdx.x == 0) {
        float s = 0.0f;
#pragma unroll
        for (int i = 0; i < 8; ++i) s += sm[i];
        norm2[k] = s;
    }
}

extern "C" void kernel_launch(void* const* d_in, const int* in_sizes, int n_in,
                              void* d_out, int out_size, void* d_ws, size_t ws_size,
                              hipStream_t stream) {
    const float* W   = (const float*)d_in[0];  // (K, V, 2) fp32
    const float* Ps  = (const float*)d_in[1];  // (B, WD) fp32
    const float* pos = (const float*)d_in[2];  // (B, WD) fp32
    const int*   ids = (const int*)d_in[3];    // (B, WD) int32

    float* out = (float*)d_out;                // float32[2049]

    // ws layout
    float2*       cst     = (float2*)d_ws;                         // WD*BD float2
    unsigned int* idp     = (unsigned int*)(cst + WDIM * BD);      // (WD/2)*BD u32
    float*        norm2   = (float*)(idp + (WDIM / 2) * BD);       // KD
    float*        contrib = norm2 + KD;                            // BD
    int*          mu_int  = (int*)(contrib + BD);                  // BD
    float*        scores  = (float*)(mu_int + BD);                 // KD*BD
    const size_t need = (size_t)(WDIM * BD * 2 + (WDIM / 2) * BD + KD + 2 * BD) * 4
                      + (size_t)KD * BD * 4;

    if (ws_size >= need) {
        prep_kernel<<<(BD + 255) / 256, 256, 0, stream>>>(pos, ids, cst, idp);
        half_kernel<<<KD * 2, 512, 0, stream>>>(W, idp, cst, norm2, scores);
        argmax_kernel<<<BD / 256, 256, 0, stream>>>(scores, out, mu_int);
    } else {
        scores_kernel_fb<<<BD, 1024, 0, stream>>>(W, pos, ids, out, mu_int);
        norm_kernel_fb<<<KD, 512, 0, stream>>>(W, norm2);
    }
    e_kernel<<<BD, 64, 0, stream>>>(W, Ps, pos, ids, mu_int, norm2, contrib);
    finalize_kernel<<<1, 256, 0, stream>>>(contrib, out);
}